// Round 1
// baseline (1242.498 us; speedup 1.0000x reference)
//
#include <hip/hip_runtime.h>

#define TOK 2048
#define DM 2048
#define DI 4096
#define NG 8
#define NN 128
#define NH 64
#define NP 64
#define NR 8
#define PROJ_D 10304
#define PROJ_P 10368
#define CONV_D 6144
#define LSEQ 1024

typedef unsigned short u16;
typedef __attribute__((ext_vector_type(4))) float f32x4;
typedef __attribute__((ext_vector_type(8))) short s16x8;
typedef __attribute__((ext_vector_type(4))) unsigned short u16x4;
typedef __attribute__((ext_vector_type(4))) float frag_cd;

__device__ __forceinline__ u16 f2bf(float f) {
  union { float f; unsigned u; } x; x.f = f;
  unsigned r = (x.u + 0x7FFFu + ((x.u >> 16) & 1u)) >> 16;
  return (u16)r;
}

__device__ __forceinline__ float blockReduceSum256(float s) {
  __shared__ float red[4];
  #pragma unroll
  for (int o = 32; o > 0; o >>= 1) s += __shfl_down(s, o, 64);
  int lane = threadIdx.x & 63, wid = threadIdx.x >> 6;
  if (lane == 0) red[wid] = s;
  __syncthreads();
  return red[0] + red[1] + red[2] + red[3];
}

// ---------- fp32 -> bf16 weight conversion with zero padding ----------
__global__ __launch_bounds__(256) void cvt_bf16_pad(const float* __restrict__ src, u16* __restrict__ dst,
                                                    long n_src, long n_dst) {
  long i = ((long)blockIdx.x * 256 + threadIdx.x) * 4;
  if (i >= n_dst) return;
  u16x4 o;
  if (i < n_src) {
    f32x4 v = *(const f32x4*)&src[i];
    o.x = f2bf(v.x); o.y = f2bf(v.y); o.z = f2bf(v.z); o.w = f2bf(v.w);
  } else {
    o.x = 0; o.y = 0; o.z = 0; o.w = 0;
  }
  *(u16x4*)&dst[i] = o;
}

// ---------- h = hs + residual; new_residual = h; x = rmsnorm(h)*w -> bf16 ----------
__global__ __launch_bounds__(256) void addnorm_kernel(const float* __restrict__ hs, const float* __restrict__ res,
        const float* __restrict__ w, float* __restrict__ nres, u16* __restrict__ xbf) {
  int row = blockIdx.x;
  size_t base = (size_t)row * DM;
  int tid = threadIdx.x;
  f32x4 h[2];
  float s = 0.f;
  #pragma unroll
  for (int i = 0; i < 2; i++) {
    int off = i * 1024 + tid * 4;
    f32x4 a = *(const f32x4*)&hs[base + off];
    f32x4 b = *(const f32x4*)&res[base + off];
    f32x4 v = a + b;
    h[i] = v;
    *(f32x4*)&nres[base + off] = v;
    s += v.x * v.x + v.y * v.y + v.z * v.z + v.w * v.w;
  }
  s = blockReduceSum256(s);
  float rs = rsqrtf(s * (1.f / DM) + 1e-5f);
  #pragma unroll
  for (int i = 0; i < 2; i++) {
    int off = i * 1024 + tid * 4;
    f32x4 wv = *(const f32x4*)&w[off];
    f32x4 v = h[i];
    u16x4 o;
    o.x = f2bf(v.x * rs * wv.x);
    o.y = f2bf(v.y * rs * wv.y);
    o.z = f2bf(v.z * rs * wv.z);
    o.w = f2bf(v.w * rs * wv.w);
    *(u16x4*)&xbf[base + off] = o;
  }
}

// ---------- bf16 GEMM, C[m][n] = sum_k A[m][k]*B[n][k]  (m97 structure) ----------
__device__ __forceinline__ void gld_lds16(const void* g, void* l) {
  __builtin_amdgcn_global_load_lds((const __attribute__((address_space(1))) void*)g,
                                   (__attribute__((address_space(3))) void*)l, 16, 0, 0);
}

__global__ __launch_bounds__(256) void gemm_bt(const u16* __restrict__ A, const u16* __restrict__ Bw,
                                               float* __restrict__ C, int K, int Cstride) {
  __shared__ u16 As[128 * 32];
  __shared__ u16 Bs[128 * 32];
  int tid = threadIdx.x;
  int lane = tid & 63, w = tid >> 6;
  int wr = w >> 1, wc = w & 1;
  size_t m0 = (size_t)blockIdx.y * 128, n0 = (size_t)blockIdx.x * 128;
  const u16* Ab = A + m0 * K;
  const u16* Bb = Bw + n0 * K;
  frag_cd acc[4][4];
  #pragma unroll
  for (int i = 0; i < 4; i++)
    #pragma unroll
    for (int j = 0; j < 4; j++) acc[i][j] = (frag_cd){0.f, 0.f, 0.f, 0.f};

  int srow = w * 16 + (lane >> 2);
  int scol = (lane & 3) * 8;
  const u16* sa = Ab + (size_t)srow * K + scol;
  const u16* sb = Bb + (size_t)srow * K + scol;
  u16* la = &As[w * 16 * 32];
  u16* lb = &Bs[w * 16 * 32];
  int ro = (lane & 15) * 32 + (lane >> 4) * 8;

  for (int k0 = 0; k0 < K; k0 += 32) {
    gld_lds16(sa + k0, la);
    gld_lds16(sa + (size_t)64 * K + k0, la + 64 * 32);
    gld_lds16(sb + k0, lb);
    gld_lds16(sb + (size_t)64 * K + k0, lb + 64 * 32);
    __syncthreads();
    s16x8 a[4], b[4];
    #pragma unroll
    for (int mi = 0; mi < 4; mi++) a[mi] = *(const s16x8*)&As[(wr * 64 + mi * 16) * 32 + ro];
    #pragma unroll
    for (int ni = 0; ni < 4; ni++) b[ni] = *(const s16x8*)&Bs[(wc * 64 + ni * 16) * 32 + ro];
    #pragma unroll
    for (int mi = 0; mi < 4; mi++)
      #pragma unroll
      for (int ni = 0; ni < 4; ni++)
        acc[mi][ni] = __builtin_amdgcn_mfma_f32_16x16x32_bf16(a[mi], b[ni], acc[mi][ni], 0, 0, 0);
    __syncthreads();
  }
  size_t crow0 = m0 + wr * 64 + ((lane >> 4) * 4);
  size_t ccol0 = n0 + wc * 64 + (lane & 15);
  #pragma unroll
  for (int mi = 0; mi < 4; mi++)
    #pragma unroll
    for (int ni = 0; ni < 4; ni++)
      #pragma unroll
      for (int j = 0; j < 4; j++)
        C[(crow0 + mi * 16 + j) * Cstride + ccol0 + ni * 16] = acc[mi][ni][j];
}

// ---------- causal depthwise conv(K=4) + bias + SiLU ----------
__global__ __launch_bounds__(256) void conv_silu_kernel(const float* __restrict__ proj,
        const float* __restrict__ cw, const float* __restrict__ cb, float* __restrict__ xbc) {
  long gid = (long)blockIdx.x * 256 + threadIdx.x;
  int c4 = (int)(gid % 1536);
  long t = gid / 1536;
  int l = (int)(t & 1023);
  int c = c4 * 4;
  const float* base = proj + (size_t)t * PROJ_P + DI + c;
  f32x4 acc = *(const f32x4*)&cb[c];
  f32x4 w0 = *(const f32x4*)&cw[(c + 0) * 4];
  f32x4 w1 = *(const f32x4*)&cw[(c + 1) * 4];
  f32x4 w2 = *(const f32x4*)&cw[(c + 2) * 4];
  f32x4 w3 = *(const f32x4*)&cw[(c + 3) * 4];
  #pragma unroll
  for (int k = 0; k < 4; k++) {
    int ls = l - 3 + k;
    if (ls >= 0) {
      f32x4 v = *(const f32x4*)(base + ((long)(k - 3)) * PROJ_P);
      acc.x = fmaf(v.x, w0[k], acc.x);
      acc.y = fmaf(v.y, w1[k], acc.y);
      acc.z = fmaf(v.z, w2[k], acc.z);
      acc.w = fmaf(v.w, w3[k], acc.w);
    }
  }
  f32x4 o;
  o.x = acc.x / (1.f + expf(-acc.x));
  o.y = acc.y / (1.f + expf(-acc.y));
  o.z = acc.z / (1.f + expf(-acc.z));
  o.w = acc.w / (1.f + expf(-acc.w));
  *(f32x4*)&xbc[(size_t)t * CONV_D + c] = o;
}

// ---------- dt softplus + dA ----------
__global__ __launch_bounds__(256) void dt_kernel(const float* __restrict__ proj, const float* __restrict__ dt_bias,
        const float* __restrict__ A_log, float* __restrict__ dtsp, float* __restrict__ dAv) {
  int idx = blockIdx.x * 256 + threadIdx.x;
  int t = idx >> 6, hh = idx & 63;
  float dtv = proj[(size_t)t * PROJ_P + (DI + CONV_D) + hh] + dt_bias[hh];
  float sp = (dtv > 15.f) ? dtv : log1pf(expf(dtv));
  float Ah = -expf(A_log[hh]);
  dtsp[idx] = sp;
  dAv[idx] = expf(sp * Ah);
}

// ---------- selective scan: block=(b,g,r), thread=(p, n-quarter), 32 state elems/lane ----------
__global__ __launch_bounds__(256) void scan_kernel(const float* __restrict__ xbc, const float* __restrict__ dtsp,
        const float* __restrict__ dAv, const float* __restrict__ Dp, float* __restrict__ y) {
  int blk = blockIdx.x;
  int b = blk >> 6, g = (blk >> 3) & 7, r = blk & 7;
  int tid = threadIdx.x;
  int p = tid >> 2, nq = tid & 3;
  int n0 = nq * 32;
  int xorv = nq << 3;  // 0,8,16,24 : bank swizzle
  __shared__ float Bsh[2][128], Csh[2][128], Xsh[2][64];
  float h[32];
  #pragma unroll
  for (int j = 0; j < 32; j++) h[j] = 0.f;
  float Dv = Dp[g * 8 + r];
  const size_t sb = (size_t)b * LSEQ * CONV_D;
  int hidx = g * 8 + r;

  // prologue: stage l=0
  {
    if (tid < 128) {
      int n = tid;
      Bsh[0][(n & 96) | ((n & 31) ^ ((n >> 2) & 24))] = xbc[sb + DI + g * NN + n];
    } else {
      int n = tid - 128;
      Csh[0][(n & 96) | ((n & 31) ^ ((n >> 2) & 24))] = xbc[sb + DI + NG * NN + g * NN + n];
    }
    if (tid < 64) Xsh[0][tid] = xbc[sb + g * 512 + r * 64 + tid];
  }
  float dtc = dtsp[(size_t)(b * LSEQ) * 64 + hidx];
  float dac = dAv[(size_t)(b * LSEQ) * 64 + hidx];
  size_t ybase = (size_t)b * LSEQ * DI + g * 512 + r * 64 + p;

  for (int l = 0; l < LSEQ; ++l) {
    __syncthreads();
    // prefetch l+1 into registers (latency hides under consume)
    float pBC = 0.f, pX = 0.f, dtn = 0.f, dan = 0.f;
    if (l + 1 < LSEQ) {
      size_t rb = sb + (size_t)(l + 1) * CONV_D;
      if (tid < 128) pBC = xbc[rb + DI + g * NN + tid];
      else pBC = xbc[rb + DI + NG * NN + g * NN + (tid - 128)];
      if (tid < 64) pX = xbc[rb + g * 512 + r * 64 + tid];
      size_t tix = (size_t)(b * LSEQ + l + 1) * 64 + hidx;
      dtn = dtsp[tix];
      dan = dAv[tix];
    }
    // consume step l
    int cur = l & 1;
    float xp = Xsh[cur][p];
    float xpd = xp * dtc;
    float acc = 0.f;
    #pragma unroll
    for (int jj = 0; jj < 8; jj++) {
      int lp = jj * 4;
      int pp = lp ^ xorv;  // physical (swizzled) offset; logical index == lp
      f32x4 bv = *(const f32x4*)&Bsh[cur][n0 + pp];
      f32x4 cv = *(const f32x4*)&Csh[cur][n0 + pp];
      h[lp + 0] = fmaf(h[lp + 0], dac, bv.x * xpd); acc = fmaf(h[lp + 0], cv.x, acc);
      h[lp + 1] = fmaf(h[lp + 1], dac, bv.y * xpd); acc = fmaf(h[lp + 1], cv.y, acc);
      h[lp + 2] = fmaf(h[lp + 2], dac, bv.z * xpd); acc = fmaf(h[lp + 2], cv.z, acc);
      h[lp + 3] = fmaf(h[lp + 3], dac, bv.w * xpd); acc = fmaf(h[lp + 3], cv.w, acc);
    }
    acc += __shfl_xor(acc, 1, 64);
    acc += __shfl_xor(acc, 2, 64);
    if (nq == 0) y[ybase + (size_t)l * DI] = acc + Dv * xp;
    // write prefetched data into the other buffer
    if (l + 1 < LSEQ) {
      int nxt = cur ^ 1;
      if (tid < 128) {
        int n = tid;
        Bsh[nxt][(n & 96) | ((n & 31) ^ ((n >> 2) & 24))] = pBC;
      } else {
        int n = tid - 128;
        Csh[nxt][(n & 96) | ((n & 31) ^ ((n >> 2) & 24))] = pBC;
      }
      if (tid < 64) Xsh[nxt][tid] = pX;
    }
    dtc = dtn; dac = dan;
  }
}

// ---------- y2 = rmsnorm(y * silu(z)) * gw -> bf16 ----------
__global__ __launch_bounds__(256) void gate_kernel(const float* __restrict__ y, const float* __restrict__ proj,
        const float* __restrict__ gw, u16* __restrict__ y2) {
  int row = blockIdx.x;
  const float* yr = y + (size_t)row * DI;
  const float* zr = proj + (size_t)row * PROJ_P;  // z = proj[:, 0:4096]
  int tid = threadIdx.x;
  f32x4 v[4];
  float s = 0.f;
  #pragma unroll
  for (int i = 0; i < 4; i++) {
    int off = i * 1024 + tid * 4;
    f32x4 a = *(const f32x4*)&yr[off];
    f32x4 z = *(const f32x4*)&zr[off];
    f32x4 t;
    t.x = a.x * (z.x / (1.f + expf(-z.x)));
    t.y = a.y * (z.y / (1.f + expf(-z.y)));
    t.z = a.z * (z.z / (1.f + expf(-z.z)));
    t.w = a.w * (z.w / (1.f + expf(-z.w)));
    v[i] = t;
    s += t.x * t.x + t.y * t.y + t.z * t.z + t.w * t.w;
  }
  s = blockReduceSum256(s);
  float rs = rsqrtf(s * (1.f / DI) + 1e-5f);
  #pragma unroll
  for (int i = 0; i < 4; i++) {
    int off = i * 1024 + tid * 4;
    f32x4 wv = *(const f32x4*)&gw[off];
    u16x4 o;
    o.x = f2bf(v[i].x * rs * wv.x);
    o.y = f2bf(v[i].y * rs * wv.y);
    o.z = f2bf(v[i].z * rs * wv.z);
    o.w = f2bf(v[i].w * rs * wv.w);
    *(u16x4*)&y2[(size_t)row * DI + off] = o;
  }
}

extern "C" void kernel_launch(void* const* d_in, const int* in_sizes, int n_in,
                              void* d_out, int out_size, void* d_ws, size_t ws_size,
                              hipStream_t stream) {
  (void)in_sizes; (void)n_in; (void)out_size; (void)ws_size;
  const float* hs      = (const float*)d_in[0];
  const float* res     = (const float*)d_in[1];
  const float* norm_w  = (const float*)d_in[2];
  const float* w_in    = (const float*)d_in[3];
  const float* conv_w  = (const float*)d_in[4];
  const float* conv_b  = (const float*)d_in[5];
  const float* A_log   = (const float*)d_in[6];
  const float* D_param = (const float*)d_in[7];
  const float* dt_bias = (const float*)d_in[8];
  const float* gate_w  = (const float*)d_in[9];
  const float* w_out   = (const float*)d_in[10];

  float* out  = (float*)d_out;
  float* nres = out + (size_t)TOK * DM;   // second output: new_residual

  char* ws = (char*)d_ws;
  size_t off = 0;
  u16*   WB1  = (u16*)(ws + off);   off += (size_t)PROJ_P * DM * 2;      // 42.5 MB
  u16*   WB2  = (u16*)(ws + off);   off += (size_t)DM * DI * 2;          // 16.8 MB
  u16*   XBF  = (u16*)(ws + off);   off += (size_t)TOK * DM * 2;         // 8.4 MB
  float* PROJ = (float*)(ws + off); off += (size_t)TOK * PROJ_P * 4;     // 84.9 MB
  float* XBC  = (float*)(ws + off); off += (size_t)TOK * CONV_D * 4;     // 50.3 MB
  float* DTSP = (float*)(ws + off); off += (size_t)TOK * 64 * 4;
  float* DAV  = (float*)(ws + off); off += (size_t)TOK * 64 * 4;
  float* Y    = (float*)(ws + off); off += (size_t)TOK * DI * 4;         // 33.6 MB
  u16*   Y2   = (u16*)(ws + off);   off += (size_t)TOK * DI * 2;         // 16.8 MB

  // weight conversions
  cvt_bf16_pad<<<20736, 256, 0, stream>>>(w_in, WB1, (long)PROJ_D * DM, (long)PROJ_P * DM);
  cvt_bf16_pad<<<8192, 256, 0, stream>>>(w_out, WB2, (long)DM * DI, (long)DM * DI);
  // residual add + rmsnorm
  addnorm_kernel<<<TOK, 256, 0, stream>>>(hs, res, norm_w, nres, XBF);
  // in_proj GEMM: (2048 x 2048) x (10368 x 2048)^T -> 2048 x 10368
  gemm_bt<<<dim3(PROJ_P / 128, TOK / 128), 256, 0, stream>>>(XBF, WB1, PROJ, DM, PROJ_P);
  // conv + silu on xBC slice
  conv_silu_kernel<<<(TOK * (CONV_D / 4)) / 256, 256, 0, stream>>>(PROJ, conv_w, conv_b, XBC);
  // dt softplus + dA
  dt_kernel<<<(TOK * 64) / 256, 256, 0, stream>>>(PROJ, dt_bias, A_log, DTSP, DAV);
  // selective scan (+ D*xs)
  scan_kernel<<<128, 256, 0, stream>>>(XBC, DTSP, DAV, D_param, Y);
  // gated rmsnorm -> bf16
  gate_kernel<<<TOK, 256, 0, stream>>>(Y, PROJ, gate_w, Y2);
  // out_proj GEMM: (2048 x 4096) x (2048 x 4096)^T -> 2048 x 2048
  gemm_bt<<<dim3(DM / 128, TOK / 128), 256, 0, stream>>>(Y2, WB2, out, DI, DM);
}

// Round 2
// 725.672 us; speedup vs baseline: 1.7122x; 1.7122x over previous
//
#include <hip/hip_runtime.h>

#define TOK 2048
#define DM 2048
#define DI 4096
#define NG 8
#define NN 128
#define NH 64
#define NP 64
#define NR 8
#define PROJ_D 10304
#define PROJ_P 10368
#define CONV_D 6144
#define LSEQ 1024
#define T_TILE 16
#define NTILES (LSEQ / T_TILE)

typedef unsigned short u16;
typedef __attribute__((ext_vector_type(4))) float f32x4;
typedef __attribute__((ext_vector_type(8))) short s16x8;
typedef __attribute__((ext_vector_type(4))) unsigned short u16x4;
typedef __attribute__((ext_vector_type(4))) float frag_cd;

__device__ __forceinline__ u16 f2bf(float f) {
  union { float f; unsigned u; } x; x.f = f;
  unsigned r = (x.u + 0x7FFFu + ((x.u >> 16) & 1u)) >> 16;
  return (u16)r;
}

__device__ __forceinline__ float blockReduceSum256(float s) {
  __shared__ float red[4];
  #pragma unroll
  for (int o = 32; o > 0; o >>= 1) s += __shfl_down(s, o, 64);
  int lane = threadIdx.x & 63, wid = threadIdx.x >> 6;
  if (lane == 0) red[wid] = s;
  __syncthreads();
  return red[0] + red[1] + red[2] + red[3];
}

// ---------- fp32 -> bf16 weight conversion with zero padding ----------
__global__ __launch_bounds__(256) void cvt_bf16_pad(const float* __restrict__ src, u16* __restrict__ dst,
                                                    long n_src, long n_dst) {
  long i = ((long)blockIdx.x * 256 + threadIdx.x) * 4;
  if (i >= n_dst) return;
  u16x4 o;
  if (i < n_src) {
    f32x4 v = *(const f32x4*)&src[i];
    o.x = f2bf(v.x); o.y = f2bf(v.y); o.z = f2bf(v.z); o.w = f2bf(v.w);
  } else {
    o.x = 0; o.y = 0; o.z = 0; o.w = 0;
  }
  *(u16x4*)&dst[i] = o;
}

// ---------- h = hs + residual; new_residual = h; x = rmsnorm(h)*w -> bf16 ----------
__global__ __launch_bounds__(256) void addnorm_kernel(const float* __restrict__ hs, const float* __restrict__ res,
        const float* __restrict__ w, float* __restrict__ nres, u16* __restrict__ xbf) {
  int row = blockIdx.x;
  size_t base = (size_t)row * DM;
  int tid = threadIdx.x;
  f32x4 h[2];
  float s = 0.f;
  #pragma unroll
  for (int i = 0; i < 2; i++) {
    int off = i * 1024 + tid * 4;
    f32x4 a = *(const f32x4*)&hs[base + off];
    f32x4 b = *(const f32x4*)&res[base + off];
    f32x4 v = a + b;
    h[i] = v;
    *(f32x4*)&nres[base + off] = v;
    s += v.x * v.x + v.y * v.y + v.z * v.z + v.w * v.w;
  }
  s = blockReduceSum256(s);
  float rs = rsqrtf(s * (1.f / DM) + 1e-5f);
  #pragma unroll
  for (int i = 0; i < 2; i++) {
    int off = i * 1024 + tid * 4;
    f32x4 wv = *(const f32x4*)&w[off];
    f32x4 v = h[i];
    u16x4 o;
    o.x = f2bf(v.x * rs * wv.x);
    o.y = f2bf(v.y * rs * wv.y);
    o.z = f2bf(v.z * rs * wv.z);
    o.w = f2bf(v.w * rs * wv.w);
    *(u16x4*)&xbf[base + off] = o;
  }
}

// ---------- bf16 GEMM, C[m][n] = sum_k A[m][k]*B[n][k]  (m97 structure) ----------
__device__ __forceinline__ void gld_lds16(const void* g, void* l) {
  __builtin_amdgcn_global_load_lds((const __attribute__((address_space(1))) void*)g,
                                   (__attribute__((address_space(3))) void*)l, 16, 0, 0);
}

__global__ __launch_bounds__(256) void gemm_bt(const u16* __restrict__ A, const u16* __restrict__ Bw,
                                               float* __restrict__ C, int K, int Cstride) {
  __shared__ u16 As[128 * 32];
  __shared__ u16 Bs[128 * 32];
  int tid = threadIdx.x;
  int lane = tid & 63, w = tid >> 6;
  int wr = w >> 1, wc = w & 1;
  size_t m0 = (size_t)blockIdx.y * 128, n0 = (size_t)blockIdx.x * 128;
  const u16* Ab = A + m0 * K;
  const u16* Bb = Bw + n0 * K;
  frag_cd acc[4][4];
  #pragma unroll
  for (int i = 0; i < 4; i++)
    #pragma unroll
    for (int j = 0; j < 4; j++) acc[i][j] = (frag_cd){0.f, 0.f, 0.f, 0.f};

  int srow = w * 16 + (lane >> 2);
  int scol = (lane & 3) * 8;
  const u16* sa = Ab + (size_t)srow * K + scol;
  const u16* sb = Bb + (size_t)srow * K + scol;
  u16* la = &As[w * 16 * 32];
  u16* lb = &Bs[w * 16 * 32];
  int ro = (lane & 15) * 32 + (lane >> 4) * 8;

  for (int k0 = 0; k0 < K; k0 += 32) {
    gld_lds16(sa + k0, la);
    gld_lds16(sa + (size_t)64 * K + k0, la + 64 * 32);
    gld_lds16(sb + k0, lb);
    gld_lds16(sb + (size_t)64 * K + k0, lb + 64 * 32);
    __syncthreads();
    s16x8 a[4], b[4];
    #pragma unroll
    for (int mi = 0; mi < 4; mi++) a[mi] = *(const s16x8*)&As[(wr * 64 + mi * 16) * 32 + ro];
    #pragma unroll
    for (int ni = 0; ni < 4; ni++) b[ni] = *(const s16x8*)&Bs[(wc * 64 + ni * 16) * 32 + ro];
    #pragma unroll
    for (int mi = 0; mi < 4; mi++)
      #pragma unroll
      for (int ni = 0; ni < 4; ni++)
        acc[mi][ni] = __builtin_amdgcn_mfma_f32_16x16x32_bf16(a[mi], b[ni], acc[mi][ni], 0, 0, 0);
    __syncthreads();
  }
  size_t crow0 = m0 + wr * 64 + ((lane >> 4) * 4);
  size_t ccol0 = n0 + wc * 64 + (lane & 15);
  #pragma unroll
  for (int mi = 0; mi < 4; mi++)
    #pragma unroll
    for (int ni = 0; ni < 4; ni++)
      #pragma unroll
      for (int j = 0; j < 4; j++)
        C[(crow0 + mi * 16 + j) * Cstride + ccol0 + ni * 16] = acc[mi][ni][j];
}

// ---------- causal depthwise conv(K=4) + bias + SiLU ----------
__global__ __launch_bounds__(256) void conv_silu_kernel(const float* __restrict__ proj,
        const float* __restrict__ cw, const float* __restrict__ cb, float* __restrict__ xbc) {
  long gid = (long)blockIdx.x * 256 + threadIdx.x;
  int c4 = (int)(gid % 1536);
  long t = gid / 1536;
  int l = (int)(t & 1023);
  int c = c4 * 4;
  const float* base = proj + (size_t)t * PROJ_P + DI + c;
  f32x4 acc = *(const f32x4*)&cb[c];
  f32x4 w0 = *(const f32x4*)&cw[(c + 0) * 4];
  f32x4 w1 = *(const f32x4*)&cw[(c + 1) * 4];
  f32x4 w2 = *(const f32x4*)&cw[(c + 2) * 4];
  f32x4 w3 = *(const f32x4*)&cw[(c + 3) * 4];
  #pragma unroll
  for (int k = 0; k < 4; k++) {
    int ls = l - 3 + k;
    if (ls >= 0) {
      f32x4 v = *(const f32x4*)(base + ((long)(k - 3)) * PROJ_P);
      acc.x = fmaf(v.x, w0[k], acc.x);
      acc.y = fmaf(v.y, w1[k], acc.y);
      acc.z = fmaf(v.z, w2[k], acc.z);
      acc.w = fmaf(v.w, w3[k], acc.w);
    }
  }
  f32x4 o;
  o.x = acc.x / (1.f + expf(-acc.x));
  o.y = acc.y / (1.f + expf(-acc.y));
  o.z = acc.z / (1.f + expf(-acc.z));
  o.w = acc.w / (1.f + expf(-acc.w));
  *(f32x4*)&xbc[(size_t)t * CONV_D + c] = o;
}

// ---------- dt softplus + dA, written TRANSPOSED [b*64+h][L] ----------
__global__ __launch_bounds__(256) void dt_kernel(const float* __restrict__ proj, const float* __restrict__ dt_bias,
        const float* __restrict__ A_log, float* __restrict__ dtspT, float* __restrict__ dAvT) {
  int idx = blockIdx.x * 256 + threadIdx.x;
  int t = idx >> 6, hh = idx & 63;
  int b = t >> 10, l = t & 1023;
  float dtv = proj[(size_t)t * PROJ_P + (DI + CONV_D) + hh] + dt_bias[hh];
  float sp = (dtv > 15.f) ? dtv : log1pf(expf(dtv));
  float Ah = -expf(A_log[hh]);
  size_t o = (size_t)(b * 64 + hh) * LSEQ + l;
  dtspT[o] = sp;
  dAvT[o] = expf(sp * Ah);
}

// ---------- selective scan, time-tiled ----------
// grid = 256 blocks: logical (pair = b*8+g, sub = r*2+ps); bid&7 == pair&7 -> same XCD shares B/C stream
// block: 256 threads = 32 pl (p within 32-slice) x 8 nq; per-thread n = {j*32 + nq*4 + e}, h[16]
__device__ __forceinline__ void stage_tile(const float* __restrict__ xb, int l0, int g, int r, int p0,
                                           float* BshT, float* CshT, float* XshT, int wv, int lane) {
  for (int c = wv; c < 18; c += 4) {
    if (c < 8) {
      int row = c * 2 + (lane >> 5);
      int col = (lane & 31) * 4;
      gld_lds16(xb + (size_t)(l0 + row) * CONV_D + DI + g * 128 + col, BshT + c * 256);
    } else if (c < 16) {
      int cc = c - 8;
      int row = cc * 2 + (lane >> 5);
      int col = (lane & 31) * 4;
      gld_lds16(xb + (size_t)(l0 + row) * CONV_D + DI + 1024 + g * 128 + col, CshT + cc * 256);
    } else {
      int cc = c - 16;
      int row = cc * 8 + (lane >> 3);
      int col = (lane & 7) * 4;
      gld_lds16(xb + (size_t)(l0 + row) * CONV_D + g * 512 + r * 64 + p0 + col, XshT + cc * 256);
    }
  }
}

__global__ __launch_bounds__(256) void scan_kernel(const float* __restrict__ xbc, const float* __restrict__ dtspT,
        const float* __restrict__ dAvT, const float* __restrict__ Dp, float* __restrict__ y) {
  int bid = blockIdx.x;
  int xcd = bid & 7, s = bid >> 3;
  int pair = xcd | ((s >> 4) << 3);   // 0..15 = b*8+g
  int sub = s & 15;                   // r*2+ps
  int b = pair >> 3, g = pair & 7;
  int r = sub >> 1, ps = sub & 1;
  int p0 = ps * 32;
  int tid = threadIdx.x;
  int wv = tid >> 6, lane = tid & 63;
  int pl = tid >> 3, nq = tid & 7;

  __shared__ float Bsh[2][T_TILE][128];
  __shared__ float Csh[2][T_TILE][128];
  __shared__ float Xsh[2][T_TILE][32];
  __shared__ float Dtsh[LSEQ];
  __shared__ float Dash[LSEQ];

  float h[16];
  #pragma unroll
  for (int j = 0; j < 16; j++) h[j] = 0.f;
  int hidx = g * 8 + r;
  float Dv = Dp[hidx];
  const float* xb = xbc + (size_t)b * LSEQ * CONV_D;

  // one-time: whole dt/dA trace for this head -> LDS
  {
    const float* dtrow = dtspT + (size_t)(b * 64 + hidx) * LSEQ;
    const float* darow = dAvT + (size_t)(b * 64 + hidx) * LSEQ;
    f32x4 v = *(const f32x4*)&dtrow[tid * 4];
    f32x4 u = *(const f32x4*)&darow[tid * 4];
    *(f32x4*)&Dtsh[tid * 4] = v;
    *(f32x4*)&Dash[tid * 4] = u;
  }
  // prologue: stage tile 0
  stage_tile(xb, 0, g, r, p0, &Bsh[0][0][0], &Csh[0][0][0], &Xsh[0][0][0], wv, lane);
  __syncthreads();

  size_t ybase = (size_t)b * LSEQ * DI + g * 512 + r * 64 + p0 + pl;

  for (int t = 0; t < NTILES; ++t) {
    int bb = t & 1;
    if (t + 1 < NTILES)
      stage_tile(xb, (t + 1) * T_TILE, g, r, p0, &Bsh[bb ^ 1][0][0], &Csh[bb ^ 1][0][0], &Xsh[bb ^ 1][0][0], wv, lane);
    int l0 = t * T_TILE;
    #pragma unroll
    for (int i = 0; i < T_TILE; ++i) {
      int l = l0 + i;
      float dtc = Dtsh[l];
      float dac = Dash[l];
      float xp = Xsh[bb][i][pl];
      float xpd = xp * dtc;
      f32x4 a4 = {0.f, 0.f, 0.f, 0.f};
      #pragma unroll
      for (int j = 0; j < 4; ++j) {
        f32x4 bv = *(const f32x4*)&Bsh[bb][i][j * 32 + nq * 4];
        f32x4 cv = *(const f32x4*)&Csh[bb][i][j * 32 + nq * 4];
        h[j * 4 + 0] = fmaf(h[j * 4 + 0], dac, bv.x * xpd); a4.x = fmaf(h[j * 4 + 0], cv.x, a4.x);
        h[j * 4 + 1] = fmaf(h[j * 4 + 1], dac, bv.y * xpd); a4.y = fmaf(h[j * 4 + 1], cv.y, a4.y);
        h[j * 4 + 2] = fmaf(h[j * 4 + 2], dac, bv.z * xpd); a4.z = fmaf(h[j * 4 + 2], cv.z, a4.z);
        h[j * 4 + 3] = fmaf(h[j * 4 + 3], dac, bv.w * xpd); a4.w = fmaf(h[j * 4 + 3], cv.w, a4.w);
      }
      float acc = (a4.x + a4.y) + (a4.z + a4.w);
      acc += __shfl_xor(acc, 1, 64);
      acc += __shfl_xor(acc, 2, 64);
      acc += __shfl_xor(acc, 4, 64);
      if (nq == 0) y[ybase + (size_t)l * DI] = fmaf(Dv, xp, acc);
    }
    __syncthreads();
  }
}

// ---------- y2 = rmsnorm(y * silu(z)) * gw -> bf16 ----------
__global__ __launch_bounds__(256) void gate_kernel(const float* __restrict__ y, const float* __restrict__ proj,
        const float* __restrict__ gw, u16* __restrict__ y2) {
  int row = blockIdx.x;
  const float* yr = y + (size_t)row * DI;
  const float* zr = proj + (size_t)row * PROJ_P;  // z = proj[:, 0:4096]
  int tid = threadIdx.x;
  f32x4 v[4];
  float s = 0.f;
  #pragma unroll
  for (int i = 0; i < 4; i++) {
    int off = i * 1024 + tid * 4;
    f32x4 a = *(const f32x4*)&yr[off];
    f32x4 z = *(const f32x4*)&zr[off];
    f32x4 t;
    t.x = a.x * (z.x / (1.f + expf(-z.x)));
    t.y = a.y * (z.y / (1.f + expf(-z.y)));
    t.z = a.z * (z.z / (1.f + expf(-z.z)));
    t.w = a.w * (z.w / (1.f + expf(-z.w)));
    v[i] = t;
    s += t.x * t.x + t.y * t.y + t.z * t.z + t.w * t.w;
  }
  s = blockReduceSum256(s);
  float rs = rsqrtf(s * (1.f / DI) + 1e-5f);
  #pragma unroll
  for (int i = 0; i < 4; i++) {
    int off = i * 1024 + tid * 4;
    f32x4 wv = *(const f32x4*)&gw[off];
    u16x4 o;
    o.x = f2bf(v[i].x * rs * wv.x);
    o.y = f2bf(v[i].y * rs * wv.y);
    o.z = f2bf(v[i].z * rs * wv.z);
    o.w = f2bf(v[i].w * rs * wv.w);
    *(u16x4*)&y2[(size_t)row * DI + off] = o;
  }
}

extern "C" void kernel_launch(void* const* d_in, const int* in_sizes, int n_in,
                              void* d_out, int out_size, void* d_ws, size_t ws_size,
                              hipStream_t stream) {
  (void)in_sizes; (void)n_in; (void)out_size; (void)ws_size;
  const float* hs      = (const float*)d_in[0];
  const float* res     = (const float*)d_in[1];
  const float* norm_w  = (const float*)d_in[2];
  const float* w_in    = (const float*)d_in[3];
  const float* conv_w  = (const float*)d_in[4];
  const float* conv_b  = (const float*)d_in[5];
  const float* A_log   = (const float*)d_in[6];
  const float* D_param = (const float*)d_in[7];
  const float* dt_bias = (const float*)d_in[8];
  const float* gate_w  = (const float*)d_in[9];
  const float* w_out   = (const float*)d_in[10];

  float* out  = (float*)d_out;
  float* nres = out + (size_t)TOK * DM;   // second output: new_residual

  char* ws = (char*)d_ws;
  size_t off = 0;
  u16*   WB1  = (u16*)(ws + off);   off += (size_t)PROJ_P * DM * 2;      // 42.5 MB
  u16*   WB2  = (u16*)(ws + off);   off += (size_t)DM * DI * 2;          // 16.8 MB
  u16*   XBF  = (u16*)(ws + off);   off += (size_t)TOK * DM * 2;         // 8.4 MB
  float* PROJ = (float*)(ws + off); off += (size_t)TOK * PROJ_P * 4;     // 84.9 MB
  float* XBC  = (float*)(ws + off); off += (size_t)TOK * CONV_D * 4;     // 50.3 MB
  float* DTSP = (float*)(ws + off); off += (size_t)TOK * 64 * 4;
  float* DAV  = (float*)(ws + off); off += (size_t)TOK * 64 * 4;
  float* Y    = (float*)(ws + off); off += (size_t)TOK * DI * 4;         // 33.6 MB
  u16*   Y2   = (u16*)(ws + off);   off += (size_t)TOK * DI * 2;         // 16.8 MB

  // weight conversions
  cvt_bf16_pad<<<20736, 256, 0, stream>>>(w_in, WB1, (long)PROJ_D * DM, (long)PROJ_P * DM);
  cvt_bf16_pad<<<8192, 256, 0, stream>>>(w_out, WB2, (long)DM * DI, (long)DM * DI);
  // residual add + rmsnorm
  addnorm_kernel<<<TOK, 256, 0, stream>>>(hs, res, norm_w, nres, XBF);
  // in_proj GEMM: (2048 x 2048) x (10368 x 2048)^T -> 2048 x 10368
  gemm_bt<<<dim3(PROJ_P / 128, TOK / 128), 256, 0, stream>>>(XBF, WB1, PROJ, DM, PROJ_P);
  // conv + silu on xBC slice
  conv_silu_kernel<<<(TOK * (CONV_D / 4)) / 256, 256, 0, stream>>>(PROJ, conv_w, conv_b, XBC);
  // dt softplus + dA (transposed layout)
  dt_kernel<<<(TOK * 64) / 256, 256, 0, stream>>>(PROJ, dt_bias, A_log, DTSP, DAV);
  // selective scan (+ D*xs), time-tiled
  scan_kernel<<<256, 256, 0, stream>>>(XBC, DTSP, DAV, D_param, Y);
  // gated rmsnorm -> bf16
  gate_kernel<<<TOK, 256, 0, stream>>>(Y, PROJ, gate_w, Y2);
  // out_proj GEMM: (2048 x 4096) x (2048 x 4096)^T -> 2048 x 2048
  gemm_bt<<<dim3(DM / 128, TOK / 128), 256, 0, stream>>>(Y2, WB2, out, DI, DM);
}